// Round 16
// baseline (136.541 us; speedup 1.0000x reference)
//
#include <hip/hip_runtime.h>

// Chamfer forward: dist0[i] = min_j ||pc0[i]-pc1[j]||^2 ; out = mean(dist0[dist0<=2])
// N = M = 65536 i.i.d. N(0,1)^3 points, fp32.
// R16 = R13 base (134.9us verified best; R15 ray-probe reverted: +1.4,
// refuting the pending-tail model a second time) + ONE change: query's
// candidate scan restructured from 9 SEQUENTIAL row-loops (compiler can't
// interleave across dynamic trip counts -> ~9-round dependent L2 chain) to
// ROUND-ROBIN ROW INTERLEAVING: 9 cursors, each outer round issues <=1
// candidate load from every non-exhausted row (9 independent loads in
// flight), then folds the mins. Chain depth Sigma(rounds_row)~9-11 ->
// max(rounds_row)~3-5, zero extra traffic (same loads, reordered). fminf is
// order-independent -> identical results. Predict query ~33->~22-25, total
// ~124-129us; if neutral, query is issue/throughput-bound = structural floor.
// CLOSED FAMILIES: grid.sync fusion (R6), pending multi-wave split (R10/R11),
// producer-consumer spin fusion (R12), q-sort removal (R14), ray-probe (R15).

constexpr int   NPTS  = 65536;
constexpr int   G     = 64;
constexpr int   NC    = G * G * G;    // 262144 fine cells
constexpr float H     = 0.125f;
constexpr float ORG   = -4.0f;
constexpr float INVH  = 8.0f;
constexpr int   G3    = 32;           // medium geometry (phase 2 rings)
constexpr float H3    = 0.25f;
constexpr float INVH3 = 4.0f;
constexpr int   BLOCK = 256;
constexpr int   PBLOCKS = 1024;       // pending grid: 4096 waves >= pending count
constexpr int   SB    = 128;          // scan blocks per fine array
constexpr int   CHUNK = NC / SB;      // 2048 counts per scan block (2/thread)

__device__ __forceinline__ int cellOf(float x) {
  int c = (int)floorf((x - ORG) * INVH);
  return min(max(c, 0), G - 1);
}
__device__ __forceinline__ int cellOf3(float x) {
  int c = (int)floorf((x - ORG) * INVH3);
  return min(max(c, 0), G3 - 1);
}

__global__ __launch_bounds__(BLOCK) void count_kernel(
    const float* __restrict__ pc0, const float* __restrict__ pc1,
    unsigned* __restrict__ counts0, unsigned* __restrict__ counts1) {
  const int gid = blockIdx.x * BLOCK + threadIdx.x;
  const float* p; unsigned* cnt; int i;
  if (gid < NPTS) { p = pc1; cnt = counts1; i = gid; }
  else            { p = pc0; cnt = counts0; i = gid - NPTS; }
  const float x = p[3 * i], y = p[3 * i + 1], z = p[3 * i + 2];
  atomicAdd(&cnt[(cellOf(z) * G + cellOf(y)) * G + cellOf(x)], 1u);
}

// Phase A: per-block partial sums. grid=(SB,2); y=0->counts1, y=1->counts0.
__global__ __launch_bounds__(1024) void scan_partial_kernel(
    const unsigned* __restrict__ counts0, const unsigned* __restrict__ counts1,
    unsigned* __restrict__ partials) {
  const unsigned* counts = blockIdx.y ? counts0 : counts1;
  const int base = blockIdx.x * CHUNK + threadIdx.x * 2;
  unsigned sum = counts[base] + counts[base + 1];
  for (int o = 32; o; o >>= 1) sum += __shfl_down(sum, o, 64);
  __shared__ unsigned ws[16];
  if ((threadIdx.x & 63) == 0) ws[threadIdx.x >> 6] = sum;
  __syncthreads();
  if (threadIdx.x == 0) {
    unsigned t = 0;
    for (int w = 0; w < 16; ++w) t += ws[w];
    partials[blockIdx.y * SB + blockIdx.x] = t;
  }
}

// Phase C: block scan + self-computed partial prefix -> cur (CSR starts).
// grid=(SB,2). partials holds RAW per-block sums (no scan_mid dispatch);
// each block masked-reduces the first blockIdx.x entries of its half.
__global__ __launch_bounds__(1024) void scan_final_kernel(
    const unsigned* __restrict__ counts0, unsigned* __restrict__ cur0,
    const unsigned* __restrict__ counts1, unsigned* __restrict__ cur1,
    const unsigned* __restrict__ partials) {
  const unsigned* counts = blockIdx.y ? counts0 : counts1;
  unsigned* cur          = blockIdx.y ? cur0    : cur1;
  const int tid = threadIdx.x;
  __shared__ unsigned blockOff;
  if (tid < 64) {                      // wave 0: exclusive prefix at x
    const int x = blockIdx.x;
    const unsigned a = (tid      < x) ? partials[blockIdx.y * SB + tid]      : 0u;
    const unsigned b = (tid + 64 < x) ? partials[blockIdx.y * SB + tid + 64] : 0u;
    unsigned t = a + b;
    for (int o = 32; o; o >>= 1) t += __shfl_down(t, o, 64);
    if (tid == 0) blockOff = t;
  }
  const int base = blockIdx.x * CHUNK + tid * 2;
  const unsigned a = counts[base], b = counts[base + 1];
  const unsigned tsum = a + b;
  unsigned inc = tsum;
  for (int o = 1; o < 64; o <<= 1) {
    const unsigned t = __shfl_up(inc, o, 64);
    if ((tid & 63) >= o) inc += t;
  }
  __shared__ unsigned wt[16];
  if ((tid & 63) == 63) wt[tid >> 6] = inc;
  __syncthreads();
  if (tid < 16) {
    unsigned w = wt[tid];
    for (int o = 1; o < 16; o <<= 1) {
      const unsigned t = __shfl_up(w, o, 16);
      if (tid >= o) w += t;
    }
    wt[tid] = w;
  }
  __syncthreads();
  const unsigned woff = (tid >> 6) ? wt[(tid >> 6) - 1] : 0u;
  const unsigned off = blockOff + woff + inc - tsum;
  cur[base] = off;
  cur[base + 1] = off + a;
}

// After scatter, cur[c] = CSR inclusive end of cell c (start = cur[c-1]).
__global__ __launch_bounds__(BLOCK) void scatter_kernel(
    const float* __restrict__ pc0, const float* __restrict__ pc1,
    unsigned* __restrict__ cur0, unsigned* __restrict__ cur1,
    float4* __restrict__ q, float4* __restrict__ s) {
  const int gid = blockIdx.x * BLOCK + threadIdx.x;
  const float* p; unsigned* cur; float4* dst; int i;
  if (gid < NPTS) { p = pc1; cur = cur1; dst = s; i = gid; }
  else            { p = pc0; cur = cur0; dst = q; i = gid - NPTS; }
  const float x = p[3 * i], y = p[3 * i + 1], z = p[3 * i + 2];
  const int cid = (cellOf(z) * G + cellOf(y)) * G + cellOf(x);
  dst[atomicAdd(&cur[cid], 1u)] = make_float4(x, y, z, 0.f);
}

// Phase 1: fine rings 0..1, 4 lanes per query; push unfinished to worklist.
// NEW: round-robin row interleaving -- 9 cursors, each outer round issues
// <=1 candidate load per non-exhausted row (independent loads in flight),
// then folds mins. Same candidate set, order-independent min.
// Exactness bound = per-point distance to the unscanned exterior (dbox, R8).
__global__ __launch_bounds__(BLOCK) void query_kernel(
    const float4* __restrict__ q, const unsigned* __restrict__ ends,
    const float4* __restrict__ s,
    unsigned* __restrict__ wl, float* __restrict__ wlBest,
    unsigned* __restrict__ pendCnt, float* __restrict__ bkt) {
  const int gtid = blockIdx.x * BLOCK + threadIdx.x;
  const int i   = gtid >> 2;        // query index
  const int sub = gtid & 3;         // sub-lane (4 per query)
  const float4 p = q[i];
  const int cx = cellOf(p.x), cy = cellOf(p.y), cz = cellOf(p.z);
  const int x0 = max(cx - 1, 0), x1 = min(cx + 1, G - 1);

  unsigned cur[9], re[9];
#pragma unroll
  for (int rr = 0; rr < 9; ++rr) {
    const int zz = cz + rr / 3 - 1, yy = cy + rr % 3 - 1;
    const bool ok = (zz >= 0) && (zz < G) && (yy >= 0) && (yy < G);
    const int rb = ok ? (zz * G + yy) * G : 0;
    const unsigned rs = ok ? ((rb + x0) ? ends[rb + x0 - 1] : 0u) : 0u;
    re[rr]  = ok ? ends[rb + x1] : 0u;
    cur[rr] = rs + sub;
  }
  float best = 3.4e38f;
  for (;;) {
    float4 cd[9];
    bool   hv[9];
    bool any = false;
#pragma unroll
    for (int rr = 0; rr < 9; ++rr) {        // issue phase: independent loads
      hv[rr] = cur[rr] < re[rr];
      if (hv[rr]) { cd[rr] = s[cur[rr]]; cur[rr] += 4; any = true; }
    }
    if (!any) break;
#pragma unroll
    for (int rr = 0; rr < 9; ++rr) {        // fold phase
      if (hv[rr]) {
        const float dx = p.x - cd[rr].x, dy = p.y - cd[rr].y,
                    dz = p.z - cd[rr].z;
        best = fminf(best, fmaf(dx, dx, fmaf(dy, dy, dz * dz)));
      }
    }
  }
  // combine the 4 sub-lanes (lanes i*4 .. i*4+3 are in the same wave)
  best = fminf(best, __shfl_xor(best, 1, 64));
  best = fminf(best, __shfl_xor(best, 2, 64));

  float v = 0.f, c = 0.f;
  if (sub == 0) {
    // dbox = min distance from p to the unscanned exterior of the scanned
    // 3x3x3 fine box (domain-clamped faces = +inf; no points beyond them).
    const int y0 = max(cy - 1, 0), y1 = min(cy + 1, G - 1);
    const int z0 = max(cz - 1, 0), z1 = min(cz + 1, G - 1);
    const float dxl = (x0 == 0)     ? 1e9f : p.x - (ORG + (float)x0 * H);
    const float dxr = (x1 == G - 1) ? 1e9f : (ORG + (float)(x1 + 1) * H) - p.x;
    const float dyl = (y0 == 0)     ? 1e9f : p.y - (ORG + (float)y0 * H);
    const float dyr = (y1 == G - 1) ? 1e9f : (ORG + (float)(y1 + 1) * H) - p.y;
    const float dzl = (z0 == 0)     ? 1e9f : p.z - (ORG + (float)z0 * H);
    const float dzr = (z1 == G - 1) ? 1e9f : (ORG + (float)(z1 + 1) * H) - p.z;
    const float dbox = fminf(fminf(fminf(dxl, dxr), fminf(dyl, dyr)),
                             fminf(dzl, dzr));
    const float bnd2 = dbox * dbox * 0.999999f;   // conservative vs rounding
    if (best > bnd2) {             // not provably exact -> phase 2
      const unsigned k = atomicAdd(pendCnt, 1u);
      wl[k] = (unsigned)i; wlBest[k] = best;
    } else if (best <= 2.0f) { v = best; c = 1.0f; }
  }

  for (int o = 32; o; o >>= 1) {
    v += __shfl_down(v, o, 64);
    c += __shfl_down(c, o, 64);
  }
  __shared__ float wsum[BLOCK / 64], wcnt[BLOCK / 64];
  const int wid = threadIdx.x >> 6;
  if ((threadIdx.x & 63) == 0) { wsum[wid] = v; wcnt[wid] = c; }
  __syncthreads();
  if (threadIdx.x == 0) {
    float bv = 0.f, bc = 0.f;
    for (int w = 0; w < BLOCK / 64; ++w) { bv += wsum[w]; bc += wcnt[w]; }
    if (bc != 0.f) {
      atomicAdd(&bkt[2 * (blockIdx.x & 63) + 0], bv);
      atomicAdd(&bkt[2 * (blockIdx.x & 63) + 1], bc);
    }
  }
}

// Phase 2: one wave per pending query; MEDIUM ring geometry over the FINE CSR
// (one medium row = 4 fine rows). Ring 1 = full 3x3x3 medium; r=8 head always
// terminates. Branch-and-bound row prune -- exact, verified R3/R8.
__global__ __launch_bounds__(BLOCK) void pending_kernel(
    const float4* __restrict__ q,
    const unsigned* __restrict__ ends, const float4* __restrict__ s,
    const unsigned* __restrict__ wl, const float* __restrict__ wlBest,
    unsigned* __restrict__ pendCnt, float* __restrict__ bkt,
    unsigned* __restrict__ done, float* __restrict__ out) {
  __shared__ int snP;
  __shared__ float wsum[BLOCK / 64], wcnt[BLOCK / 64];
  __shared__ int isLast;
  __shared__ float fs[BLOCK / 64], fc[BLOCK / 64];
  if (threadIdx.x == 0) snP = (int)atomicAdd(pendCnt, 0u);
  __syncthreads();
  const int lane = threadIdx.x & 63, wid = threadIdx.x >> 6;
  const int gw = blockIdx.x * (BLOCK / 64) + wid;
  const int nW = PBLOCKS * (BLOCK / 64);
  float v = 0.f, c = 0.f;

  for (int it = gw; it < snP; it += nW) {
    const unsigned qi = wl[it];
    const float4 p = q[qi];
    const int cx = cellOf3(p.x), cy = cellOf3(p.y), cz = cellOf3(p.z);
    float best = wlBest[it];   // wave-uniform (same address)

    for (int r = 1; r <= 8; ++r) {
      const float cov = H3 * (float)(r - 1);    // unscanned dist lower bound
      if (best <= cov * cov) break;             // exact
      if (best > 2.0f && cov * cov >= 2.0f) break;  // masked out either way
      const int S = (r == 1) ? 9 : 8 * r + 2 * (2 * r - 1) * (2 * r - 1);
      float b = best;
      for (int sI = lane; sI < S; sI += 64) {
        int dz, dy, xa, xb;
        if (r == 1) {                           // full 3x3x3 medium rows
          dz = sI / 3 - 1; dy = sI % 3 - 1; xa = cx - 1; xb = cx + 1;
        } else if (sI < 8 * r) {                // shell faces: full x rows
          if (sI < 2 * r + 1)      { dz = -r; dy = sI - r; }
          else if (sI < 4 * r + 2) { dz =  r; dy = sI - (2 * r + 1) - r; }
          else { const int t2 = sI - (4 * r + 2); dz = (t2 >> 1) - (r - 1);
                 dy = (t2 & 1) ? r : -r; }
          xa = cx - r; xb = cx + r;
        } else {                                // interior rows: x = +/- r ends
          const int t2 = sI - 8 * r, ci = t2 >> 1, w1 = 2 * r - 1;
          dz = ci / w1 - (r - 1); dy = ci % w1 - (r - 1);
          xa = xb = (t2 & 1) ? cx + r : cx - r;
        }
        const int Z = cz + dz, Y = cy + dy;
        if (Z < 0 || Z >= G3 || Y < 0 || Y >= G3) continue;
        int a3 = max(xa, 0), e3 = min(xb, G3 - 1);
        if (a3 > e3) continue;
        // --- branch-and-bound row prune (exact) -------------------------
        const float ylo = ORG + (float)Y * H3;
        const float zlo = ORG + (float)Z * H3;
        const float dyd = fmaxf(fmaxf(ylo - p.y, p.y - (ylo + H3)), 0.f);
        const float dzd = fmaxf(fmaxf(zlo - p.z, p.z - (zlo + H3)), 0.f);
        const float dyz2 = dyd * dyd + dzd * dzd;
        const float bnd = fminf(b, 2.0f);
        if (dyz2 >= bnd) continue;
        const float halfx = sqrtf(bnd - dyz2);
        const int xlo = (int)floorf((p.x - halfx - ORG) * INVH3);
        const int xhi = (int)floorf((p.x + halfx - ORG) * INVH3);
        a3 = max(a3, xlo); e3 = min(e3, xhi);
        if (a3 > e3) continue;
        // ----------------------------------------------------------------
        const int xs = 2 * a3, xe = 2 * e3 + 1; // fine x-span
        // 4 fine rows per medium row; ranges preloaded (independent loads)
        unsigned js[4], je[4];
#pragma unroll
        for (int k = 0; k < 4; ++k) {
          const int zz = 2 * Z + (k >> 1), yy = 2 * Y + (k & 1);
          const int rb = (zz * G + yy) * G;
          js[k] = (rb + xs) ? ends[rb + xs - 1] : 0u;
          je[k] = ends[rb + xe];
        }
#pragma unroll
        for (int k = 0; k < 4; ++k) {
#pragma unroll 4
          for (unsigned j = js[k]; j < je[k]; ++j) {
            const float4 cd = s[j];
            const float dx = p.x - cd.x, dyv = p.y - cd.y, dzv = p.z - cd.z;
            b = fminf(b, fmaf(dx, dx, fmaf(dyv, dyv, dzv * dzv)));
          }
        }
      }
      for (int o = 32; o; o >>= 1) b = fminf(b, __shfl_xor(b, o, 64));
      best = b;                                 // wave-uniform again
    }
    if (lane == 0 && best <= 2.0f) { v += best; c += 1.0f; }
  }

  if (lane == 0) { wsum[wid] = v; wcnt[wid] = c; }
  __syncthreads();
  if (threadIdx.x == 0) {
    float bv = 0.f, bc = 0.f;
    for (int w = 0; w < BLOCK / 64; ++w) { bv += wsum[w]; bc += wcnt[w]; }
    if (bc != 0.f) {
      atomicAdd(&bkt[2 * (blockIdx.x & 63) + 0], bv);
      atomicAdd(&bkt[2 * (blockIdx.x & 63) + 1], bc);
    }
    __threadfence();
    isLast = (atomicAdd(done, 1u) == (unsigned)(PBLOCKS - 1));
  }
  __syncthreads();
  if (isLast) {   // parallel coherent read of the 128 bucket slots + reduce
    const float val = (threadIdx.x < 128) ? atomicAdd(&bkt[threadIdx.x], 0.0f) : 0.0f;
    float sv = (threadIdx.x & 1) ? 0.f : val;
    float cv = (threadIdx.x & 1) ? val : 0.f;
    for (int o = 32; o; o >>= 1) {
      sv += __shfl_down(sv, o, 64);
      cv += __shfl_down(cv, o, 64);
    }
    if (lane == 0) { fs[wid] = sv; fc[wid] = cv; }
    __syncthreads();
    if (threadIdx.x == 0) {
      float S = 0.f, C = 0.f;
      for (int w = 0; w < BLOCK / 64; ++w) { S += fs[w]; C += fc[w]; }
      out[0] = S / C;
    }
  }
}

extern "C" void kernel_launch(void* const* d_in, const int* in_sizes, int n_in,
                              void* d_out, int out_size, void* d_ws, size_t ws_size,
                              hipStream_t stream) {
  const float* pc0 = (const float*)d_in[0];
  const float* pc1 = (const float*)d_in[1];
  float* out = (float*)d_out;

  // slab carve-up; counts1|counts0|misc contiguous -> single memset
  char* w = (char*)d_ws;
  auto nxt = [&](size_t bytes) {
    char* p = w; w += (bytes + 255) & ~(size_t)255; return p;
  };
  unsigned* counts1  = (unsigned*)nxt((size_t)NC * 4);           // 1 MB
  unsigned* counts0  = (unsigned*)nxt((size_t)NC * 4);           // 1 MB
  char*     misc     = nxt(1024);   // bkt[128] | done | pendCnt
  float*    bkt      = (float*)misc;
  unsigned* done     = (unsigned*)(misc + 512);
  unsigned* pendCnt  = (unsigned*)(misc + 516);
  unsigned* partials = (unsigned*)nxt((size_t)2 * SB * 4);       // 1 KB
  unsigned* cur1     = (unsigned*)nxt((size_t)NC * 4);           // 1 MB
  unsigned* cur0     = (unsigned*)nxt((size_t)NC * 4);           // 1 MB
  float4*   s        = (float4*)nxt((size_t)NPTS * 16);          // 1 MB
  float4*   q        = (float4*)nxt((size_t)NPTS * 16);          // 1 MB
  unsigned* wl       = (unsigned*)nxt((size_t)NPTS * 4);         // 256 KB
  float*    wlBest   = (float*)nxt((size_t)NPTS * 4);            // 256 KB

  hipMemsetAsync(counts1, 0, (size_t)2 * NC * 4 + 1024, stream);

  count_kernel<<<2 * NPTS / BLOCK, BLOCK, 0, stream>>>(pc0, pc1, counts0, counts1);
  scan_partial_kernel<<<dim3(SB, 2), 1024, 0, stream>>>(counts0, counts1, partials);
  scan_final_kernel<<<dim3(SB, 2), 1024, 0, stream>>>(counts0, cur0,
                                                      counts1, cur1, partials);
  scatter_kernel<<<2 * NPTS / BLOCK, BLOCK, 0, stream>>>(
      pc0, pc1, cur0, cur1, q, s);
  query_kernel<<<4 * NPTS / BLOCK, BLOCK, 0, stream>>>(q, cur1, s, wl, wlBest,
                                                       pendCnt, bkt);
  pending_kernel<<<PBLOCKS, BLOCK, 0, stream>>>(q, cur1, s, wl, wlBest,
                                                pendCnt, bkt, done, out);
}

// Round 17
// 133.858 us; speedup vs baseline: 1.0200x; 1.0200x over previous
//
#include <hip/hip_runtime.h>

// Chamfer forward: dist0[i] = min_j ||pc0[i]-pc1[j]||^2 ; out = mean(dist0[dist0<=2])
// N = M = 65536 i.i.d. N(0,1)^3 points, fp32.
// R17 = FINAL: exact revert to R13 (134.9us, session best, verified).
// Session map: 148.2 -> 134.9 via exact-pruning family (R3 pending B&B
// prune -6.3; R8 dbox bound -2.5; R13 scan_mid delete -2) + query 4-sublane
// (R2). All other families CLOSED with counter evidence:
//  - query interior: +TLP (R7 +7.3), volume cut (R9 +1.1), row-interleave
//    (R16 +1.6) -> issue/L2-throughput-bound structural floor (~33us).
//  - pending restructure: 4-wave split (R10 258us / R11 280us), ray-probe
//    seed (R15 +1.4) -> one-wave-per-item + B&B prune is optimal form.
//  - cross-block coordination: coop grid.sync (R6 262us), spin
//    producer-consumer (R12 385us) -> catastrophic on this platform
//    (signature: occ ~42%, VALUBusy ~2%, waves resident+idle).
//  - q-sort removal (R14 +10.9) -> sorted-q wave locality is load-bearing.
// Fixed overhead: harness poison-fill ~41us @ 82% HBM peak (serialized,
// confirmed via R12 accounting). Remaining ~94us spread over 6 latency-bound
// dispatches, each at its tested floor. Practical floor reached.

constexpr int   NPTS  = 65536;
constexpr int   G     = 64;
constexpr int   NC    = G * G * G;    // 262144 fine cells
constexpr float H     = 0.125f;
constexpr float ORG   = -4.0f;
constexpr float INVH  = 8.0f;
constexpr int   G3    = 32;           // medium geometry (phase 2 rings)
constexpr float H3    = 0.25f;
constexpr float INVH3 = 4.0f;
constexpr int   BLOCK = 256;
constexpr int   PBLOCKS = 1024;       // pending grid: 4096 waves >= pending count
constexpr int   SB    = 128;          // scan blocks per fine array
constexpr int   CHUNK = NC / SB;      // 2048 counts per scan block (2/thread)

__device__ __forceinline__ int cellOf(float x) {
  int c = (int)floorf((x - ORG) * INVH);
  return min(max(c, 0), G - 1);
}
__device__ __forceinline__ int cellOf3(float x) {
  int c = (int)floorf((x - ORG) * INVH3);
  return min(max(c, 0), G3 - 1);
}

__global__ __launch_bounds__(BLOCK) void count_kernel(
    const float* __restrict__ pc0, const float* __restrict__ pc1,
    unsigned* __restrict__ counts0, unsigned* __restrict__ counts1) {
  const int gid = blockIdx.x * BLOCK + threadIdx.x;
  const float* p; unsigned* cnt; int i;
  if (gid < NPTS) { p = pc1; cnt = counts1; i = gid; }
  else            { p = pc0; cnt = counts0; i = gid - NPTS; }
  const float x = p[3 * i], y = p[3 * i + 1], z = p[3 * i + 2];
  atomicAdd(&cnt[(cellOf(z) * G + cellOf(y)) * G + cellOf(x)], 1u);
}

// Phase A: per-block partial sums. grid=(SB,2); y=0->counts1, y=1->counts0.
__global__ __launch_bounds__(1024) void scan_partial_kernel(
    const unsigned* __restrict__ counts0, const unsigned* __restrict__ counts1,
    unsigned* __restrict__ partials) {
  const unsigned* counts = blockIdx.y ? counts0 : counts1;
  const int base = blockIdx.x * CHUNK + threadIdx.x * 2;
  unsigned sum = counts[base] + counts[base + 1];
  for (int o = 32; o; o >>= 1) sum += __shfl_down(sum, o, 64);
  __shared__ unsigned ws[16];
  if ((threadIdx.x & 63) == 0) ws[threadIdx.x >> 6] = sum;
  __syncthreads();
  if (threadIdx.x == 0) {
    unsigned t = 0;
    for (int w = 0; w < 16; ++w) t += ws[w];
    partials[blockIdx.y * SB + blockIdx.x] = t;
  }
}

// Phase C: block scan + self-computed partial prefix -> cur (CSR starts).
// grid=(SB,2). partials holds RAW per-block sums (no scan_mid dispatch);
// each block masked-reduces the first blockIdx.x entries of its half.
__global__ __launch_bounds__(1024) void scan_final_kernel(
    const unsigned* __restrict__ counts0, unsigned* __restrict__ cur0,
    const unsigned* __restrict__ counts1, unsigned* __restrict__ cur1,
    const unsigned* __restrict__ partials) {
  const unsigned* counts = blockIdx.y ? counts0 : counts1;
  unsigned* cur          = blockIdx.y ? cur0    : cur1;
  const int tid = threadIdx.x;
  __shared__ unsigned blockOff;
  if (tid < 64) {                      // wave 0: exclusive prefix at x
    const int x = blockIdx.x;
    const unsigned a = (tid      < x) ? partials[blockIdx.y * SB + tid]      : 0u;
    const unsigned b = (tid + 64 < x) ? partials[blockIdx.y * SB + tid + 64] : 0u;
    unsigned t = a + b;
    for (int o = 32; o; o >>= 1) t += __shfl_down(t, o, 64);
    if (tid == 0) blockOff = t;
  }
  const int base = blockIdx.x * CHUNK + tid * 2;
  const unsigned a = counts[base], b = counts[base + 1];
  const unsigned tsum = a + b;
  unsigned inc = tsum;
  for (int o = 1; o < 64; o <<= 1) {
    const unsigned t = __shfl_up(inc, o, 64);
    if ((tid & 63) >= o) inc += t;
  }
  __shared__ unsigned wt[16];
  if ((tid & 63) == 63) wt[tid >> 6] = inc;
  __syncthreads();
  if (tid < 16) {
    unsigned w = wt[tid];
    for (int o = 1; o < 16; o <<= 1) {
      const unsigned t = __shfl_up(w, o, 16);
      if (tid >= o) w += t;
    }
    wt[tid] = w;
  }
  __syncthreads();
  const unsigned woff = (tid >> 6) ? wt[(tid >> 6) - 1] : 0u;
  const unsigned off = blockOff + woff + inc - tsum;
  cur[base] = off;
  cur[base + 1] = off + a;
}

// After scatter, cur[c] = CSR inclusive end of cell c (start = cur[c-1]).
__global__ __launch_bounds__(BLOCK) void scatter_kernel(
    const float* __restrict__ pc0, const float* __restrict__ pc1,
    unsigned* __restrict__ cur0, unsigned* __restrict__ cur1,
    float4* __restrict__ q, float4* __restrict__ s) {
  const int gid = blockIdx.x * BLOCK + threadIdx.x;
  const float* p; unsigned* cur; float4* dst; int i;
  if (gid < NPTS) { p = pc1; cur = cur1; dst = s; i = gid; }
  else            { p = pc0; cur = cur0; dst = q; i = gid - NPTS; }
  const float x = p[3 * i], y = p[3 * i + 1], z = p[3 * i + 2];
  const int cid = (cellOf(z) * G + cellOf(y)) * G + cellOf(x);
  dst[atomicAdd(&cur[cid], 1u)] = make_float4(x, y, z, 0.f);
}

// Phase 1: fine rings 0..1, 4 lanes per query; push unfinished to worklist.
// Exactness bound = per-point distance to the unscanned exterior (dbox, R8).
__global__ __launch_bounds__(BLOCK) void query_kernel(
    const float4* __restrict__ q, const unsigned* __restrict__ ends,
    const float4* __restrict__ s,
    unsigned* __restrict__ wl, float* __restrict__ wlBest,
    unsigned* __restrict__ pendCnt, float* __restrict__ bkt) {
  const int gtid = blockIdx.x * BLOCK + threadIdx.x;
  const int i   = gtid >> 2;        // query index
  const int sub = gtid & 3;         // sub-lane (4 per query)
  const float4 p = q[i];
  const int cx = cellOf(p.x), cy = cellOf(p.y), cz = cellOf(p.z);
  const int x0 = max(cx - 1, 0), x1 = min(cx + 1, G - 1);

  unsigned rs[9], re[9];
#pragma unroll
  for (int rr = 0; rr < 9; ++rr) {
    const int zz = cz + rr / 3 - 1, yy = cy + rr % 3 - 1;
    const bool ok = (zz >= 0) && (zz < G) && (yy >= 0) && (yy < G);
    const int rb = ok ? (zz * G + yy) * G : 0;
    rs[rr] = ok ? ((rb + x0) ? ends[rb + x0 - 1] : 0u) : 0u;
    re[rr] = ok ? ends[rb + x1] : 0u;
  }
  float best = 3.4e38f;
#pragma unroll
  for (int rr = 0; rr < 9; ++rr) {
#pragma unroll 4
    for (unsigned j = rs[rr] + sub; j < re[rr]; j += 4) {
      const float4 c = s[j];
      const float dx = p.x - c.x, dy = p.y - c.y, dz = p.z - c.z;
      best = fminf(best, fmaf(dx, dx, fmaf(dy, dy, dz * dz)));
    }
  }
  // combine the 4 sub-lanes (lanes i*4 .. i*4+3 are in the same wave)
  best = fminf(best, __shfl_xor(best, 1, 64));
  best = fminf(best, __shfl_xor(best, 2, 64));

  float v = 0.f, c = 0.f;
  if (sub == 0) {
    // dbox = min distance from p to the unscanned exterior of the scanned
    // 3x3x3 fine box (domain-clamped faces = +inf; no points beyond them).
    const int y0 = max(cy - 1, 0), y1 = min(cy + 1, G - 1);
    const int z0 = max(cz - 1, 0), z1 = min(cz + 1, G - 1);
    const float dxl = (x0 == 0)     ? 1e9f : p.x - (ORG + (float)x0 * H);
    const float dxr = (x1 == G - 1) ? 1e9f : (ORG + (float)(x1 + 1) * H) - p.x;
    const float dyl = (y0 == 0)     ? 1e9f : p.y - (ORG + (float)y0 * H);
    const float dyr = (y1 == G - 1) ? 1e9f : (ORG + (float)(y1 + 1) * H) - p.y;
    const float dzl = (z0 == 0)     ? 1e9f : p.z - (ORG + (float)z0 * H);
    const float dzr = (z1 == G - 1) ? 1e9f : (ORG + (float)(z1 + 1) * H) - p.z;
    const float dbox = fminf(fminf(fminf(dxl, dxr), fminf(dyl, dyr)),
                             fminf(dzl, dzr));
    const float bnd2 = dbox * dbox * 0.999999f;   // conservative vs rounding
    if (best > bnd2) {             // not provably exact -> phase 2
      const unsigned k = atomicAdd(pendCnt, 1u);
      wl[k] = (unsigned)i; wlBest[k] = best;
    } else if (best <= 2.0f) { v = best; c = 1.0f; }
  }

  for (int o = 32; o; o >>= 1) {
    v += __shfl_down(v, o, 64);
    c += __shfl_down(c, o, 64);
  }
  __shared__ float wsum[BLOCK / 64], wcnt[BLOCK / 64];
  const int wid = threadIdx.x >> 6;
  if ((threadIdx.x & 63) == 0) { wsum[wid] = v; wcnt[wid] = c; }
  __syncthreads();
  if (threadIdx.x == 0) {
    float bv = 0.f, bc = 0.f;
    for (int w = 0; w < BLOCK / 64; ++w) { bv += wsum[w]; bc += wcnt[w]; }
    if (bc != 0.f) {
      atomicAdd(&bkt[2 * (blockIdx.x & 63) + 0], bv);
      atomicAdd(&bkt[2 * (blockIdx.x & 63) + 1], bc);
    }
  }
}

// Phase 2: one wave per pending query; MEDIUM ring geometry over the FINE CSR
// (one medium row = 4 fine rows). Ring 1 = full 3x3x3 medium; r=8 head always
// terminates. Branch-and-bound row prune (box y/z distance + x-span clip to
// the ball of radius sqrt(min(b,2)) around p) -- exact, verified R3/R8.
__global__ __launch_bounds__(BLOCK) void pending_kernel(
    const float4* __restrict__ q,
    const unsigned* __restrict__ ends, const float4* __restrict__ s,
    const unsigned* __restrict__ wl, const float* __restrict__ wlBest,
    unsigned* __restrict__ pendCnt, float* __restrict__ bkt,
    unsigned* __restrict__ done, float* __restrict__ out) {
  __shared__ int snP;
  __shared__ float wsum[BLOCK / 64], wcnt[BLOCK / 64];
  __shared__ int isLast;
  __shared__ float fs[BLOCK / 64], fc[BLOCK / 64];
  if (threadIdx.x == 0) snP = (int)atomicAdd(pendCnt, 0u);
  __syncthreads();
  const int lane = threadIdx.x & 63, wid = threadIdx.x >> 6;
  const int gw = blockIdx.x * (BLOCK / 64) + wid;
  const int nW = PBLOCKS * (BLOCK / 64);
  float v = 0.f, c = 0.f;

  for (int it = gw; it < snP; it += nW) {
    const unsigned qi = wl[it];
    const float4 p = q[qi];
    const int cx = cellOf3(p.x), cy = cellOf3(p.y), cz = cellOf3(p.z);
    float best = wlBest[it];   // wave-uniform (same address)

    for (int r = 1; r <= 8; ++r) {
      const float cov = H3 * (float)(r - 1);    // unscanned dist lower bound
      if (best <= cov * cov) break;             // exact
      if (best > 2.0f && cov * cov >= 2.0f) break;  // masked out either way
      const int S = (r == 1) ? 9 : 8 * r + 2 * (2 * r - 1) * (2 * r - 1);
      float b = best;
      for (int sI = lane; sI < S; sI += 64) {
        int dz, dy, xa, xb;
        if (r == 1) {                           // full 3x3x3 medium rows
          dz = sI / 3 - 1; dy = sI % 3 - 1; xa = cx - 1; xb = cx + 1;
        } else if (sI < 8 * r) {                // shell faces: full x rows
          if (sI < 2 * r + 1)      { dz = -r; dy = sI - r; }
          else if (sI < 4 * r + 2) { dz =  r; dy = sI - (2 * r + 1) - r; }
          else { const int t2 = sI - (4 * r + 2); dz = (t2 >> 1) - (r - 1);
                 dy = (t2 & 1) ? r : -r; }
          xa = cx - r; xb = cx + r;
        } else {                                // interior rows: x = +/- r ends
          const int t2 = sI - 8 * r, ci = t2 >> 1, w1 = 2 * r - 1;
          dz = ci / w1 - (r - 1); dy = ci % w1 - (r - 1);
          xa = xb = (t2 & 1) ? cx + r : cx - r;
        }
        const int Z = cz + dz, Y = cy + dy;
        if (Z < 0 || Z >= G3 || Y < 0 || Y >= G3) continue;
        int a3 = max(xa, 0), e3 = min(xb, G3 - 1);
        if (a3 > e3) continue;
        // --- branch-and-bound row prune (exact) -------------------------
        const float ylo = ORG + (float)Y * H3;
        const float zlo = ORG + (float)Z * H3;
        const float dyd = fmaxf(fmaxf(ylo - p.y, p.y - (ylo + H3)), 0.f);
        const float dzd = fmaxf(fmaxf(zlo - p.z, p.z - (zlo + H3)), 0.f);
        const float dyz2 = dyd * dyd + dzd * dzd;
        const float bnd = fminf(b, 2.0f);
        if (dyz2 >= bnd) continue;
        const float halfx = sqrtf(bnd - dyz2);
        const int xlo = (int)floorf((p.x - halfx - ORG) * INVH3);
        const int xhi = (int)floorf((p.x + halfx - ORG) * INVH3);
        a3 = max(a3, xlo); e3 = min(e3, xhi);
        if (a3 > e3) continue;
        // ----------------------------------------------------------------
        const int xs = 2 * a3, xe = 2 * e3 + 1; // fine x-span
        // 4 fine rows per medium row; ranges preloaded (independent loads)
        unsigned js[4], je[4];
#pragma unroll
        for (int k = 0; k < 4; ++k) {
          const int zz = 2 * Z + (k >> 1), yy = 2 * Y + (k & 1);
          const int rb = (zz * G + yy) * G;
          js[k] = (rb + xs) ? ends[rb + xs - 1] : 0u;
          je[k] = ends[rb + xe];
        }
#pragma unroll
        for (int k = 0; k < 4; ++k) {
#pragma unroll 4
          for (unsigned j = js[k]; j < je[k]; ++j) {
            const float4 cd = s[j];
            const float dx = p.x - cd.x, dyv = p.y - cd.y, dzv = p.z - cd.z;
            b = fminf(b, fmaf(dx, dx, fmaf(dyv, dyv, dzv * dzv)));
          }
        }
      }
      for (int o = 32; o; o >>= 1) b = fminf(b, __shfl_xor(b, o, 64));
      best = b;                                 // wave-uniform again
    }
    if (lane == 0 && best <= 2.0f) { v += best; c += 1.0f; }
  }

  if (lane == 0) { wsum[wid] = v; wcnt[wid] = c; }
  __syncthreads();
  if (threadIdx.x == 0) {
    float bv = 0.f, bc = 0.f;
    for (int w = 0; w < BLOCK / 64; ++w) { bv += wsum[w]; bc += wcnt[w]; }
    if (bc != 0.f) {
      atomicAdd(&bkt[2 * (blockIdx.x & 63) + 0], bv);
      atomicAdd(&bkt[2 * (blockIdx.x & 63) + 1], bc);
    }
    __threadfence();
    isLast = (atomicAdd(done, 1u) == (unsigned)(PBLOCKS - 1));
  }
  __syncthreads();
  if (isLast) {   // parallel coherent read of the 128 bucket slots + reduce
    const float val = (threadIdx.x < 128) ? atomicAdd(&bkt[threadIdx.x], 0.0f) : 0.0f;
    float sv = (threadIdx.x & 1) ? 0.f : val;
    float cv = (threadIdx.x & 1) ? val : 0.f;
    for (int o = 32; o; o >>= 1) {
      sv += __shfl_down(sv, o, 64);
      cv += __shfl_down(cv, o, 64);
    }
    if (lane == 0) { fs[wid] = sv; fc[wid] = cv; }
    __syncthreads();
    if (threadIdx.x == 0) {
      float S = 0.f, C = 0.f;
      for (int w = 0; w < BLOCK / 64; ++w) { S += fs[w]; C += fc[w]; }
      out[0] = S / C;
    }
  }
}

extern "C" void kernel_launch(void* const* d_in, const int* in_sizes, int n_in,
                              void* d_out, int out_size, void* d_ws, size_t ws_size,
                              hipStream_t stream) {
  const float* pc0 = (const float*)d_in[0];
  const float* pc1 = (const float*)d_in[1];
  float* out = (float*)d_out;

  // slab carve-up; counts1|counts0|misc contiguous -> single memset
  char* w = (char*)d_ws;
  auto nxt = [&](size_t bytes) {
    char* p = w; w += (bytes + 255) & ~(size_t)255; return p;
  };
  unsigned* counts1  = (unsigned*)nxt((size_t)NC * 4);           // 1 MB
  unsigned* counts0  = (unsigned*)nxt((size_t)NC * 4);           // 1 MB
  char*     misc     = nxt(1024);   // bkt[128] | done | pendCnt
  float*    bkt      = (float*)misc;
  unsigned* done     = (unsigned*)(misc + 512);
  unsigned* pendCnt  = (unsigned*)(misc + 516);
  unsigned* partials = (unsigned*)nxt((size_t)2 * SB * 4);       // 1 KB
  unsigned* cur1     = (unsigned*)nxt((size_t)NC * 4);           // 1 MB
  unsigned* cur0     = (unsigned*)nxt((size_t)NC * 4);           // 1 MB
  float4*   s        = (float4*)nxt((size_t)NPTS * 16);          // 1 MB
  float4*   q        = (float4*)nxt((size_t)NPTS * 16);          // 1 MB
  unsigned* wl       = (unsigned*)nxt((size_t)NPTS * 4);         // 256 KB
  float*    wlBest   = (float*)nxt((size_t)NPTS * 4);            // 256 KB

  hipMemsetAsync(counts1, 0, (size_t)2 * NC * 4 + 1024, stream);

  count_kernel<<<2 * NPTS / BLOCK, BLOCK, 0, stream>>>(pc0, pc1, counts0, counts1);
  scan_partial_kernel<<<dim3(SB, 2), 1024, 0, stream>>>(counts0, counts1, partials);
  scan_final_kernel<<<dim3(SB, 2), 1024, 0, stream>>>(counts0, cur0,
                                                      counts1, cur1, partials);
  scatter_kernel<<<2 * NPTS / BLOCK, BLOCK, 0, stream>>>(
      pc0, pc1, cur0, cur1, q, s);
  query_kernel<<<4 * NPTS / BLOCK, BLOCK, 0, stream>>>(q, cur1, s, wl, wlBest,
                                                       pendCnt, bkt);
  pending_kernel<<<PBLOCKS, BLOCK, 0, stream>>>(q, cur1, s, wl, wlBest,
                                                pendCnt, bkt, done, out);
}